// Round 1
// baseline (129.898 us; speedup 1.0000x reference)
//
#include <hip/hip_runtime.h>

#define N2 16384
#define N1 65536
#define N0 262144

// ---- workspace layout (float offsets) ----
#define WS_T2_RE   0            // [20][N2]
#define WS_T2_IM   (20*N2)
#define WS_M2P_RE  (40*N2)      // [4][N2]
#define WS_M2P_IM  (44*N2)
#define WS_P1_RE   (48*N2)      // [4][N1] = 16*N2
#define WS_P1_IM   (64*N2)
#define WS_T1_RE   (80*N2)
#define WS_T1_IM   (96*N2)
#define WS_I00_RE  (112*N2)
#define WS_I00_IM  (128*N2)
#define WS_IS1_RE  (144*N2)     // [N1] = 4*N2
#define WS_IS1_IM  (148*N2)
#define WS_LD_BYTE ((size_t)(152*N2)*4)   // double accumulator (8-aligned)

// ---- output layout (float offsets) ----
#define OUT_AIM 7225344         // 21*21*N2
#define OUT_LD  14450688        // 2*21*21*N2
#define OUT_ZRE 14450689
#define OUT_ZIM 14794753        // OUT_ZRE + 21*N2

__device__ __forceinline__ void block_reduce_atomic(float v, double* acc,
                                                    float* wsum) {
#pragma unroll
    for (int off = 32; off > 0; off >>= 1) v += __shfl_down(v, off, 64);
    const int lane = threadIdx.x & 63;
    const int wid  = threadIdx.x >> 6;
    if (lane == 0) wsum[wid] = v;
    __syncthreads();
    if (threadIdx.x == 0)
        atomicAdd(acc, (double)(wsum[0] + wsum[1] + wsum[2] + wsum[3]));
}

// One thread per m in [0, N1): fused stage-1 Schur update + stage-2 T2/M2 partials.
__global__ __launch_bounds__(256) void stage12_kernel(
    const float* __restrict__ l00r, const float* __restrict__ l00i,
    const float* __restrict__ l01r, const float* __restrict__ l01i,
    const float* __restrict__ l02r, const float* __restrict__ l02i,
    const float* __restrict__ l11r, const float* __restrict__ l11i,
    const float* __restrict__ l12r, const float* __restrict__ l12i,
    float* __restrict__ ws, double* __restrict__ ld_acc)
{
    const int m = blockIdx.x * 256 + threadIdx.x;   // 0..N1-1
    const int u = m >> 14;                          // which 16k-chunk of N1
    const int j = m & (N2 - 1);

    float ld = 0.f;
    float i0r[4], i0i[4], t1r[4], t1i[4], p1r[4], p1i[4];
    float m1r = 0.f, m1i = 0.f;
#pragma unroll
    for (int k = 0; k < 4; ++k) {
        const int i = k * N1 + m;
        const float ar = l00r[i], ai = l00i[i];
        const float br = l01r[i], bi = l01i[i];
        const float d  = ar*ar + ai*ai;
        const float rd = 1.f / d;
        ld += 0.5f * logf(d);                       // log|lam00|
        const float xr = ar * rd, xi = -ai * rd;    // inv00 = 1/lam00
        i0r[k] = xr; i0i[k] = xi;
        const float tr = br*xr - bi*xi;             // T1 = lam01/lam00
        const float ti = br*xi + bi*xr;
        t1r[k] = tr; t1i[k] = ti;
        m1r += br*tr + bi*ti;                       // conj(lam01)*T1
        m1i += br*ti - bi*tr;
    }
    const float s1r = l11r[m] - m1r;
    const float s1i = l11i[m] - m1i;
    const float ds1 = s1r*s1r + s1i*s1i;
    ld += 0.5f * logf(ds1);                         // log|S1|
    const float rds1 = 1.f / ds1;
    const float is1r = s1r * rds1, is1i = -s1i * rds1;
#pragma unroll
    for (int k = 0; k < 4; ++k) {
        p1r[k] = t1r[k]*is1r - t1i[k]*is1i;         // P1 = T1/S1
        p1i[k] = t1r[k]*is1i + t1i[k]*is1r;
    }

    // B column for stage 2: Bcol[a] = lam02[a*N1+m] (a<4), Bcol[4] = lam12[m]
    float bcr[5], bci[5];
#pragma unroll
    for (int a = 0; a < 4; ++a) { bcr[a] = l02r[a*N1+m]; bci[a] = l02i[a*N1+m]; }
    bcr[4] = l12r[m]; bci[4] = l12i[m];

    // W = sum_{b<4} Bcol[b]*conj(T1[b]) - Bcol[4]
    float wr = -bcr[4], wi = -bci[4];
#pragma unroll
    for (int b = 0; b < 4; ++b) {
        wr += bcr[b]*t1r[b] + bci[b]*t1i[b];
        wi += bci[b]*t1r[b] - bcr[b]*t1i[b];
    }
    // T2[a*4+u] = P1[a]*W + Bcol[a]*inv00[a]  (a<4);  a=4 row below
    float t2r[5], t2i[5];
#pragma unroll
    for (int a = 0; a < 4; ++a) {
        t2r[a] = p1r[a]*wr - p1i[a]*wi + bcr[a]*i0r[a] - bci[a]*i0i[a];
        t2i[a] = p1r[a]*wi + p1i[a]*wr + bcr[a]*i0i[a] + bci[a]*i0r[a];
    }
    {
        float vr = bcr[4]*is1r - bci[4]*is1i;       // Bcol[4]*invS1
        float vi = bcr[4]*is1i + bci[4]*is1r;
#pragma unroll
        for (int b = 0; b < 4; ++b) {               // - Bcol[b]*conj(P1[b])
            vr -= bcr[b]*p1r[b] + bci[b]*p1i[b];
            vi -= bci[b]*p1r[b] - bcr[b]*p1i[b];
        }
        t2r[4] = vr; t2i[4] = vi;
    }

    // store T2 rows q=a*4+u, accumulate per-u partial of M2 = sum conj(B)*T2
    float m2r = 0.f, m2i = 0.f;
#pragma unroll
    for (int a = 0; a < 5; ++a) {
        const int q = a*4 + u;
        ws[WS_T2_RE + q*N2 + j] = t2r[a];
        ws[WS_T2_IM + q*N2 + j] = t2i[a];
        m2r += bcr[a]*t2r[a] + bci[a]*t2i[a];
        m2i += bcr[a]*t2i[a] - bci[a]*t2r[a];
    }
    ws[WS_M2P_RE + u*N2 + j] = m2r;
    ws[WS_M2P_IM + u*N2 + j] = m2i;
#pragma unroll
    for (int k = 0; k < 4; ++k) {
        ws[WS_P1_RE  + k*N1 + m] = p1r[k];
        ws[WS_P1_IM  + k*N1 + m] = p1i[k];
        ws[WS_T1_RE  + k*N1 + m] = t1r[k];
        ws[WS_T1_IM  + k*N1 + m] = t1i[k];
        ws[WS_I00_RE + k*N1 + m] = i0r[k];
        ws[WS_I00_IM + k*N1 + m] = i0i[k];
    }
    ws[WS_IS1_RE + m] = is1r;
    ws[WS_IS1_IM + m] = is1i;

    __shared__ float wsum[4];
    block_reduce_atomic(ld, ld_acc, wsum);
}

// grid (N2/256, 21); thread = column j, blockIdx.y = output row p.
__global__ __launch_bounds__(256) void stage3_kernel(
    const float* __restrict__ l22r, const float* __restrict__ l22i,
    const float* __restrict__ zre, const float* __restrict__ zim,
    const float* __restrict__ ws, float* __restrict__ out,
    double* __restrict__ ld_acc)
{
    const int j = blockIdx.x * 256 + threadIdx.x;
    const int p = blockIdx.y;

    float s2r = l22r[j], s2i = l22i[j];
#pragma unroll
    for (int u = 0; u < 4; ++u) {
        s2r -= ws[WS_M2P_RE + u*N2 + j];
        s2i -= ws[WS_M2P_IM + u*N2 + j];
    }
    const float ds2  = s2r*s2r + s2i*s2i;
    const float rds2 = 1.f / ds2;
    const float is2r = s2r * rds2, is2i = -s2i * rds2;

    float zar = 0.f, zai = 0.f;
    if (p == 20) {
#pragma unroll
        for (int q = 0; q < 21; ++q) {
            float ar, ai;
            if (q < 20) {
                const float tr = ws[WS_T2_RE + q*N2 + j];
                const float ti = ws[WS_T2_IM + q*N2 + j];
                const float pr = tr*is2r - ti*is2i;   // P2[q]
                const float pi = tr*is2i + ti*is2r;
                ar = -pr; ai = pi;                    // -conj(P2[q])
            } else { ar = is2r; ai = is2i; }          // 1/S2
            out[(p*21 + q)*N2 + j]           = ar;
            out[OUT_AIM + (p*21 + q)*N2 + j] = ai;
            const float zqr = zre[q*N2 + j], zqi = zim[q*N2 + j];
            zar += zqr*ar - zqi*ai;
            zai += zqr*ai + zqi*ar;
        }
    } else {
        const int a  = p >> 2;
        const int u  = p & 3;
        const int mu = u*N2 + j;
        const float tpr = ws[WS_T2_RE + p*N2 + j];
        const float tpi = ws[WS_T2_IM + p*N2 + j];
        const float ppr = tpr*is2r - tpi*is2i;        // P2[p]
        const float ppi = tpr*is2i + tpi*is2r;
        float par=0.f, pai=0.f, ir=0.f, ii=0.f, js1r=0.f, js1i=0.f;
        float t1br[4], t1bi[4], p1br[4], p1bi[4];
        if (a < 4) {
            par = ws[WS_P1_RE  + a*N1 + mu]; pai = ws[WS_P1_IM  + a*N1 + mu];
            ir  = ws[WS_I00_RE + a*N1 + mu]; ii  = ws[WS_I00_IM + a*N1 + mu];
#pragma unroll
            for (int b = 0; b < 4; ++b) {
                t1br[b] = ws[WS_T1_RE + b*N1 + mu];
                t1bi[b] = ws[WS_T1_IM + b*N1 + mu];
            }
        } else {
#pragma unroll
            for (int b = 0; b < 4; ++b) {
                p1br[b] = ws[WS_P1_RE + b*N1 + mu];
                p1bi[b] = ws[WS_P1_IM + b*N1 + mu];
            }
            js1r = ws[WS_IS1_RE + mu]; js1i = ws[WS_IS1_IM + mu];
        }
#pragma unroll
        for (int q = 0; q < 21; ++q) {
            float ar, ai;
            if (q < 20) {
                const float tr = ws[WS_T2_RE + q*N2 + j];
                const float ti = ws[WS_T2_IM + q*N2 + j];
                ar = ppr*tr + ppi*ti;                 // P2[p]*conj(T2[q])
                ai = ppi*tr - ppr*ti;
                if ((q & 3) == u) {                   // scatter of A1[a][b]
                    const int b = q >> 2;
                    if (a < 4) {
                        if (b < 4) {
                            ar += par*t1br[b] + pai*t1bi[b];   // P1[a]*conj(T1[b])
                            ai += pai*t1br[b] - par*t1bi[b];
                            if (b == a) { ar += ir; ai += ii; } // + 1/lam00
                        } else { ar -= par; ai -= pai; }        // -P1[a]
                    } else {
                        if (b < 4) { ar -= p1br[b]; ai += p1bi[b]; } // -conj(P1[b])
                        else       { ar += js1r; ai += js1i; }       // 1/S1
                    }
                }
            } else { ar = -ppr; ai = -ppi; }          // -P2[p]
            out[(p*21 + q)*N2 + j]           = ar;
            out[OUT_AIM + (p*21 + q)*N2 + j] = ai;
            const float zqr = zre[q*N2 + j], zqi = zim[q*N2 + j];
            zar += zqr*ar - zqi*ai;
            zai += zqr*ai + zqi*ar;
        }
    }
    out[OUT_ZRE + p*N2 + j] = zar;
    out[OUT_ZIM + p*N2 + j] = zai;

    if (p == 0) {
        __shared__ float wsum[4];
        block_reduce_atomic(0.5f * logf(ds2), ld_acc, wsum);
    }
}

__global__ void finalize_kernel(const double* __restrict__ acc,
                                float* __restrict__ out) {
    out[OUT_LD] = (float)(*acc);
}

extern "C" void kernel_launch(void* const* d_in, const int* in_sizes, int n_in,
                              void* d_out, int out_size, void* d_ws, size_t ws_size,
                              hipStream_t stream)
{
    const float* l00r = (const float*)d_in[0];
    const float* l00i = (const float*)d_in[1];
    const float* l01r = (const float*)d_in[2];
    const float* l01i = (const float*)d_in[3];
    const float* l02r = (const float*)d_in[4];
    const float* l02i = (const float*)d_in[5];
    const float* l11r = (const float*)d_in[6];
    const float* l11i = (const float*)d_in[7];
    const float* l12r = (const float*)d_in[8];
    const float* l12i = (const float*)d_in[9];
    const float* l22r = (const float*)d_in[10];
    const float* l22i = (const float*)d_in[11];
    const float* zre  = (const float*)d_in[12];
    const float* zim  = (const float*)d_in[13];
    float*  out    = (float*)d_out;
    float*  ws     = (float*)d_ws;
    double* ld_acc = (double*)((char*)d_ws + WS_LD_BYTE);

    hipMemsetAsync(ld_acc, 0, sizeof(double), stream);
    stage12_kernel<<<dim3(N1/256), dim3(256), 0, stream>>>(
        l00r,l00i,l01r,l01i,l02r,l02i,l11r,l11i,l12r,l12i, ws, ld_acc);
    stage3_kernel<<<dim3(N2/256, 21), dim3(256), 0, stream>>>(
        l22r,l22i,zre,zim, ws, out, ld_acc);
    finalize_kernel<<<1, 1, 0, stream>>>(ld_acc, out);
}